// Round 17
// baseline (10891.534 us; speedup 1.0000x reference)
//
#include <hip/hip_runtime.h>
#include <math.h>

// Problem dims
#define TT 128
#define BB 512
#define EE 100
#define HH 256
#define G4 1024
#define NTAG 20

#define KW 384            // p3 K padded (356 -> 384)
#define KQ 256            // p1 K
#define KR 128            // p2 K padded (100 -> 128, zero weights past 100)
#define NW (1024*KW)      // 393216 elems per split
#define NQ (112*KQ)       // 28672
#define NR (256*KR)       // 32768

typedef short bf16x8 __attribute__((ext_vector_type(8)));
typedef float f32x4  __attribute__((ext_vector_type(4)));
#define MFMA16(a,b,c) __builtin_amdgcn_mfma_f32_16x16x32_bf16((a),(b),(c),0,0,0)
#define MM6(ACC,AH,AM,AL,BH,BM,BL) { \
    ACC = MFMA16(AH,BH,ACC); ACC = MFMA16(AH,BM,ACC); ACC = MFMA16(AM,BH,ACC); \
    ACC = MFMA16(AH,BL,ACC); ACC = MFMA16(AL,BH,ACC); ACC = MFMA16(AM,BM,ACC); }

__device__ __forceinline__ float sigm(float x){ return 1.f/(1.f+expf(-x)); }

// Exact-ish fp32 -> 3x bf16 split by truncation (24 mantissa bits captured).
__device__ __forceinline__ void split3(float v, unsigned short&a, unsigned short&b, unsigned short&c){
    unsigned u0 = __float_as_uint(v); a = (unsigned short)(u0>>16);
    float r1 = v - __uint_as_float(u0 & 0xFFFF0000u);
    unsigned u1 = __float_as_uint(r1); b = (unsigned short)(u1>>16);
    float r2 = r1 - __uint_as_float(u1 & 0xFFFF0000u);
    c = (unsigned short)(__float_as_uint(r2)>>16);
}

// ---------------------------------------------------------------------------
// prep8 (one direction): bf16x3-split weight arrays (unchanged from R15/R16).
// ---------------------------------------------------------------------------
__global__ void prep8(const float* __restrict__ Wih, const float* __restrict__ Whh,
                      const float* __restrict__ bih, const float* __restrict__ bhh,
                      const float* __restrict__ Q, const float* __restrict__ R,
                      unsigned short* __restrict__ Ws, unsigned short* __restrict__ Qs,
                      unsigned short* __restrict__ Rs, float* __restrict__ bP)
{
    int idx = blockIdx.x * blockDim.x + threadIdx.x;
    float v; unsigned short* dst; int str;
    if (idx < NW) {
        int n = idx / KW, k = idx - n * KW;
        v = (k < EE) ? Wih[n*EE + k] : (k < EE+HH) ? Whh[n*HH + (k-EE)] : 0.f;
        dst = Ws + idx; str = NW;
    } else if (idx < NW + NQ) {
        int i = idx - NW; int e = i >> 8, k = i & 255;
        v = (e < EE) ? Q[k*EE + e] : 0.f;
        dst = Qs + i; str = NQ;
    } else if (idx < NW + NQ + NR) {
        int i = idx - (NW + NQ); int j = i >> 7, k = i & 127;
        v = (k < EE) ? R[k*HH + j] : 0.f;
        dst = Rs + i; str = NR;
    } else if (idx < NW + NQ + NR + G4) {
        int n = idx - (NW + NQ + NR); bP[n] = bih[n] + bhh[n]; return;
    } else return;
    unsigned short a,b,c; split3(v,a,b,c);
    dst[0] = a; dst[str] = b; dst[2*str] = c;
}

// ---- phase-3 macros: SINGLE 4-tile W buffer (48 VGPR), product-major -------
#define LDQ(Q0,Q1,Q2,Q3, AO) { \
    WH0 = *(const bf16x8*)(Q0 + (AO));        WH1 = *(const bf16x8*)(Q1 + (AO)); \
    WH2 = *(const bf16x8*)(Q2 + (AO));        WH3 = *(const bf16x8*)(Q3 + (AO)); \
    WM0 = *(const bf16x8*)(Q0 + NW + (AO));   WM1 = *(const bf16x8*)(Q1 + NW + (AO)); \
    WM2 = *(const bf16x8*)(Q2 + NW + (AO));   WM3 = *(const bf16x8*)(Q3 + NW + (AO)); \
    WL0 = *(const bf16x8*)(Q0 + 2*NW + (AO)); WL1 = *(const bf16x8*)(Q1 + 2*NW + (AO)); \
    WL2 = *(const bf16x8*)(Q2 + 2*NW + (AO)); WL3 = *(const bf16x8*)(Q3 + 2*NW + (AO)); }

#define MMQ(QB) { \
    acc[QB+0]=MFMA16(ah,WH0,acc[QB+0]); acc[QB+1]=MFMA16(ah,WH1,acc[QB+1]); \
    acc[QB+2]=MFMA16(ah,WH2,acc[QB+2]); acc[QB+3]=MFMA16(ah,WH3,acc[QB+3]); \
    acc[QB+0]=MFMA16(ah,WM0,acc[QB+0]); acc[QB+1]=MFMA16(ah,WM1,acc[QB+1]); \
    acc[QB+2]=MFMA16(ah,WM2,acc[QB+2]); acc[QB+3]=MFMA16(ah,WM3,acc[QB+3]); \
    acc[QB+0]=MFMA16(am,WH0,acc[QB+0]); acc[QB+1]=MFMA16(am,WH1,acc[QB+1]); \
    acc[QB+2]=MFMA16(am,WH2,acc[QB+2]); acc[QB+3]=MFMA16(am,WH3,acc[QB+3]); \
    acc[QB+0]=MFMA16(ah,WL0,acc[QB+0]); acc[QB+1]=MFMA16(ah,WL1,acc[QB+1]); \
    acc[QB+2]=MFMA16(ah,WL2,acc[QB+2]); acc[QB+3]=MFMA16(ah,WL3,acc[QB+3]); \
    acc[QB+0]=MFMA16(al,WH0,acc[QB+0]); acc[QB+1]=MFMA16(al,WH1,acc[QB+1]); \
    acc[QB+2]=MFMA16(al,WH2,acc[QB+2]); acc[QB+3]=MFMA16(al,WH3,acc[QB+3]); \
    acc[QB+0]=MFMA16(am,WM0,acc[QB+0]); acc[QB+1]=MFMA16(am,WM1,acc[QB+1]); \
    acc[QB+2]=MFMA16(am,WM2,acc[QB+2]); acc[QB+3]=MFMA16(am,WM3,acc[QB+3]); }

// ---------------------------------------------------------------------------
// MFMA recurrence (structure = R15/R16, proven absmax 0). Phase 3 register-
// slimmed: single-quad W buffer, plain launch_bounds so the allocator can
// keep loads in flight instead of serializing (R16's 128-cap pathology).
// ---------------------------------------------------------------------------
__global__ __launch_bounds__(512) void lstm13(
    const int* __restrict__ words, const float* __restrict__ embed,
    const unsigned short* __restrict__ Qsf, const unsigned short* __restrict__ Rsf,
    const unsigned short* __restrict__ Wsf, const float* __restrict__ bPf,
    const unsigned short* __restrict__ Qsb, const unsigned short* __restrict__ Rsb,
    const unsigned short* __restrict__ Wsb, const float* __restrict__ bPb,
    float* hfbuf, float* hbbuf)
{
    const int bid = blockIdx.x;
    const int dir = bid & 1;
    const int cb  = bid >> 1;        // 0..31
    const int b0  = cb * 16;
    const int tid = threadIdx.x;
    const int wv  = tid >> 6;        // wave 0..7
    const int ln  = tid & 63;
    const int nn  = ln & 15;         // operand row/col within tile
    const int gq  = ln >> 4;         // k-block group 0..3
    const int m4  = gq * 4;          // C/D row base

    const unsigned short* Qs = dir ? Qsb : Qsf;
    const unsigned short* Rs = dir ? Rsb : Rsf;
    const unsigned short* Ws = dir ? Wsb : Wsf;
    const float* bP = dir ? bPb : bPf;
    float* hout = dir ? hbbuf : hfbuf;

    __shared__ unsigned short sA[3][16][392];   // p3/p2 A: [xm 0..99 | hm 100..355 | 0]
    __shared__ unsigned short sh3[3][16][264];  // h splits (p1 A), k 0..255
    __shared__ float sH[16*256];                // h_prev fp32
    __shared__ int sWords[16*TT];

    {   // zero split arrays (pads MUST be 0); preload word ids
        unsigned* pa = (unsigned*)&sA[0][0][0];
        for (int i = tid; i < 9408; i += 512) pa[i] = 0;
        unsigned* pb = (unsigned*)&sh3[0][0][0];
        for (int i = tid; i < 6336; i += 512) pb[i] = 0;
        for (int i = tid; i < 16*TT; i += 512)
            sWords[i] = words[(b0 + (i >> 7)) * TT + (i & 127)];
    }

    float bq[8];                     // bias for acc q (col = wv*16+nn+128q)
    #pragma unroll
    for (int q = 0; q < 8; ++q) bq[q] = bP[wv*16 + nn + q*128];
    float cc[8];                     // cell state: [grp*4 + r]
    #pragma unroll
    for (int i = 0; i < 8; ++i) cc[i] = 0.f;

    // hoisted W tile base pointers (col tile q -> base)
    const unsigned short* wb = Ws + (size_t)(wv*16 + nn) * KW;
    const unsigned short* w0 = wb;
    const unsigned short* w1 = wb + (size_t)1*(128*KW);
    const unsigned short* w2 = wb + (size_t)2*(128*KW);
    const unsigned short* w3 = wb + (size_t)3*(128*KW);
    const unsigned short* w4 = wb + (size_t)4*(128*KW);
    const unsigned short* w5 = wb + (size_t)5*(128*KW);
    const unsigned short* w6 = wb + (size_t)6*(128*KW);
    const unsigned short* w7 = wb + (size_t)7*(128*KW);

    const int koff = gq * 8;
    const f32x4 zv = {0.f, 0.f, 0.f, 0.f};
    __syncthreads();

    for (int s = 0; s < TT; ++s) {
        const int t = dir ? (TT-1-s) : s;

        // ---- phase 1: P = h@Q (MFMA); xm = 2*sig(P)*x -> sA splits --------
        if (wv < 7) {
            const int e = wv*16 + nn;
            const bool ev = (e < EE);
            float xv0=0.f, xv1=0.f, xv2=0.f, xv3=0.f;
            if (ev) {
                xv0 = embed[(size_t)sWords[(m4+0)*TT + t]*EE + e];
                xv1 = embed[(size_t)sWords[(m4+1)*TT + t]*EE + e];
                xv2 = embed[(size_t)sWords[(m4+2)*TT + t]*EE + e];
                xv3 = embed[(size_t)sWords[(m4+3)*TT + t]*EE + e];
            }
            float pr0, pr1, pr2, pr3;
            if (s > 0) {
                f32x4 pa = zv, pb = zv;    // two parity chains
                const unsigned short* qb = Qs + (size_t)e * KQ;
                #pragma unroll
                for (int ks = 0; ks < 8; ks += 2) {
                    {
                        const int ao = ks*32 + koff;
                        bf16x8 ah = *(const bf16x8*)&sh3[0][nn][ao];
                        bf16x8 am = *(const bf16x8*)&sh3[1][nn][ao];
                        bf16x8 al = *(const bf16x8*)&sh3[2][nn][ao];
                        bf16x8 bh = *(const bf16x8*)(qb + ao);
                        bf16x8 bm = *(const bf16x8*)(qb + NQ + ao);
                        bf16x8 bl = *(const bf16x8*)(qb + 2*NQ + ao);
                        MM6(pa, ah, am, al, bh, bm, bl);
                    }
                    {
                        const int ao = (ks+1)*32 + koff;
                        bf16x8 ah = *(const bf16x8*)&sh3[0][nn][ao];
                        bf16x8 am = *(const bf16x8*)&sh3[1][nn][ao];
                        bf16x8 al = *(const bf16x8*)&sh3[2][nn][ao];
                        bf16x8 bh = *(const bf16x8*)(qb + ao);
                        bf16x8 bm = *(const bf16x8*)(qb + NQ + ao);
                        bf16x8 bl = *(const bf16x8*)(qb + 2*NQ + ao);
                        MM6(pb, ah, am, al, bh, bm, bl);
                    }
                }
                f32x4 p = pa + pb;
                pr0 = 2.f*sigm(p[0])*xv0; pr1 = 2.f*sigm(p[1])*xv1;
                pr2 = 2.f*sigm(p[2])*xv2; pr3 = 2.f*sigm(p[3])*xv3;
            } else {   // h=0 -> 2*sig(0)=1 -> xm = x
                pr0 = xv0; pr1 = xv1; pr2 = xv2; pr3 = xv3;
            }
            if (ev) {
                unsigned short a,b,c;
                split3(pr0,a,b,c); sA[0][m4+0][e]=a; sA[1][m4+0][e]=b; sA[2][m4+0][e]=c;
                split3(pr1,a,b,c); sA[0][m4+1][e]=a; sA[1][m4+1][e]=b; sA[2][m4+1][e]=c;
                split3(pr2,a,b,c); sA[0][m4+2][e]=a; sA[1][m4+2][e]=b; sA[2][m4+2][e]=c;
                split3(pr3,a,b,c); sA[0][m4+3][e]=a; sA[1][m4+3][e]=b; sA[2][m4+3][e]=c;
            }
        }
        __syncthreads();

        // ---- phase 2: S = xm@R (MFMA); hm = 2*sig(S)*h_prev -> sA splits --
        // A-operand reads sA directly (k 100..127 garbage x ZERO Rs weights).
        if (s > 0) {
            f32x4 s0 = zv, s1 = zv;
            const int j0 = wv*16 + nn, j1 = j0 + 128;
            const unsigned short* rb0 = Rs + (size_t)j0 * KR;
            const unsigned short* rb1 = Rs + (size_t)j1 * KR;
            #pragma unroll
            for (int ks = 0; ks < 4; ++ks) {
                const int ao = ks*32 + koff;
                bf16x8 ah = *(const bf16x8*)&sA[0][nn][ao];
                bf16x8 am = *(const bf16x8*)&sA[1][nn][ao];
                bf16x8 al = *(const bf16x8*)&sA[2][nn][ao];
                bf16x8 b0h = *(const bf16x8*)(rb0 + ao);
                bf16x8 b0m = *(const bf16x8*)(rb0 + NR + ao);
                bf16x8 b0l = *(const bf16x8*)(rb0 + 2*NR + ao);
                MM6(s0, ah, am, al, b0h, b0m, b0l);
                bf16x8 b1h = *(const bf16x8*)(rb1 + ao);
                bf16x8 b1m = *(const bf16x8*)(rb1 + NR + ao);
                bf16x8 b1l = *(const bf16x8*)(rb1 + 2*NR + ao);
                MM6(s1, ah, am, al, b1h, b1m, b1l);
            }
            #pragma unroll
            for (int r = 0; r < 4; ++r) {
                const int row = m4 + r;
                const float hm0 = 2.f*sigm(s0[r])*sH[row*256 + j0];
                const float hm1 = 2.f*sigm(s1[r])*sH[row*256 + j1];
                unsigned short a,b,c;
                split3(hm0,a,b,c); sA[0][row][100+j0]=a; sA[1][row][100+j0]=b; sA[2][row][100+j0]=c;
                split3(hm1,a,b,c); sA[0][row][100+j1]=a; sA[1][row][100+j1]=b; sA[2][row][100+j1]=c;
            }
        }
        __syncthreads();

        // ---- phase 3: G = [xm|hm]@W (MFMA, 8 tiles/wave) ------------------
        // Single-quad W buffer (48 VGPR), product-major dep-distance-4.
        f32x4 acc[8];
        #pragma unroll
        for (int q = 0; q < 8; ++q) acc[q] = zv;
        {
            bf16x8 WH0,WH1,WH2,WH3, WM0,WM1,WM2,WM3, WL0,WL1,WL2,WL3;
            #pragma unroll
            for (int ks = 0; ks < 12; ++ks) {
                const int ao = ks*32 + koff;
                bf16x8 ah = *(const bf16x8*)&sA[0][nn][ao];
                bf16x8 am = *(const bf16x8*)&sA[1][nn][ao];
                bf16x8 al = *(const bf16x8*)&sA[2][nn][ao];
                LDQ(w0,w1,w2,w3, ao);
                MMQ(0);
                LDQ(w4,w5,w6,w7, ao);
                MMQ(4);
            }
        }

        // ---- phase 4: register-local cell update; h -> sH/sh3/hout --------
        #pragma unroll
        for (int grp = 0; grp < 2; ++grp) {
            const int j = wv*16 + nn + grp*128;
            #pragma unroll
            for (int r = 0; r < 4; ++r) {
                const int row = m4 + r;
                const float gi = acc[0+grp][r] + bq[0+grp];
                const float gf = acc[2+grp][r] + bq[2+grp];
                const float gg = acc[4+grp][r] + bq[4+grp];
                const float go = acc[6+grp][r] + bq[6+grp];
                const float cv = sigm(gf)*cc[grp*4+r] + sigm(gi)*tanhf(gg);
                cc[grp*4+r] = cv;
                const float hv = sigm(go)*tanhf(cv);
                sH[row*256 + j] = hv;
                unsigned short a,b,c;
                split3(hv,a,b,c);
                sh3[0][row][j] = a; sh3[1][row][j] = b; sh3[2][row][j] = c;
                __builtin_nontemporal_store(hv, &hout[((size_t)t*BB + b0 + row)*HH + j]);
            }
        }
        __syncthreads();
    }
}

// ---------------------------------------------------------------------------
// logits = [hf|hb] @ Wt^T + bt ; argmax (first index on ties) -> out[b][t]
// ---------------------------------------------------------------------------
__global__ __launch_bounds__(256) void logits_kernel(
    const float* __restrict__ hf, const float* __restrict__ hb,
    const float* __restrict__ Wt, const float* __restrict__ bt,
    int* __restrict__ out)
{
    __shared__ float sW[NTAG][2 * HH];
    __shared__ float sb[NTAG];
    const int tid = threadIdx.x;
    for (int i = tid; i < NTAG * 2 * HH; i += 256) (&sW[0][0])[i] = Wt[i];
    if (tid < NTAG) sb[tid] = bt[tid];
    __syncthreads();

    const int pos = blockIdx.x * 256 + tid;
    const int b  = pos & 511;
    const int t0 = pos >> 9;
    const int t1 = t0 + 64;

    float acc0[NTAG], acc1[NTAG];
    #pragma unroll
    for (int n = 0; n < NTAG; ++n) { acc0[n] = sb[n]; acc1[n] = sb[n]; }

    const float* f0 = hf + ((size_t)t0 * BB + b) * HH;
    const float* f1 = hf + ((size_t)t1 * BB + b) * HH;
    for (int k = 0; k < HH; k += 4) {
        const float4 a0 = *(const float4*)(f0 + k);
        const float4 a1 = *(const float4*)(f1 + k);
        #pragma unroll
        for (int n = 0; n < NTAG; ++n) {
            const float4 w = *(const float4*)&sW[n][k];
            acc0[n] += a0.x * w.x + a0.y * w.y + a0.z * w.z + a0.w * w.w;
            acc1[n] += a1.x * w.x + a1.y * w.y + a1.z * w.z + a1.w * w.w;
        }
    }
    const float* g0 = hb + ((size_t)t0 * BB + b) * HH;
    const float* g1 = hb + ((size_t)t1 * BB + b) * HH;
    for (int k = 0; k < HH; k += 4) {
        const float4 a0 = *(const float4*)(g0 + k);
        const float4 a1 = *(const float4*)(g1 + k);
        #pragma unroll
        for (int n = 0; n < NTAG; ++n) {
            const float4 w = *(const float4*)&sW[n][HH + k];
            acc0[n] += a0.x * w.x + a0.y * w.y + a0.z * w.z + a0.w * w.w;
            acc1[n] += a1.x * w.x + a1.y * w.y + a1.z * w.z + a1.w * w.w;
        }
    }

    float b0v = acc0[0]; int i0 = 0;
    float b1v = acc1[0]; int i1 = 0;
    #pragma unroll
    for (int n = 1; n < NTAG; ++n) {
        if (acc0[n] > b0v) { b0v = acc0[n]; i0 = n; }
        if (acc1[n] > b1v) { b1v = acc1[n]; i1 = n; }
    }
    out[b * TT + t0] = i0;
    out[b * TT + t1] = i1;
}

// ---------------------------------------------------------------------------
extern "C" void kernel_launch(void* const* d_in, const int* in_sizes, int n_in,
                              void* d_out, int out_size, void* d_ws, size_t ws_size,
                              hipStream_t stream)
{
    (void)in_sizes; (void)n_in; (void)out_size; (void)ws_size;

    const int*   words = (const int*)  d_in[0];
    const float* embd  = (const float*)d_in[5];
    const float* Wih_f = (const float*)d_in[6];
    const float* Whh_f = (const float*)d_in[7];
    const float* bih_f = (const float*)d_in[8];
    const float* bhh_f = (const float*)d_in[9];
    const float* Q_f   = (const float*)d_in[10];
    const float* R_f   = (const float*)d_in[11];
    const float* Wih_b = (const float*)d_in[12];
    const float* Whh_b = (const float*)d_in[13];
    const float* bih_b = (const float*)d_in[14];
    const float* bhh_b = (const float*)d_in[15];
    const float* Q_b   = (const float*)d_in[16];
    const float* R_b   = (const float*)d_in[17];
    const float* Wt    = (const float*)d_in[18];
    const float* bt    = (const float*)d_in[19];
    int* out = (int*)d_out;

    // workspace layout: hf, hb (fp32), biases, then bf16x3 split arrays (~134 MB)
    float* hf   = (float*)d_ws;
    float* hb   = hf + (size_t)TT * BB * HH;
    float* bP_f = hb + (size_t)TT * BB * HH;
    float* bP_b = bP_f + G4;
    unsigned short* Ws_f = (unsigned short*)(bP_b + G4);
    unsigned short* Qs_f = Ws_f + 3 * (size_t)NW;
    unsigned short* Rs_f = Qs_f + 3 * (size_t)NQ;
    unsigned short* Ws_b = Rs_f + 3 * (size_t)NR;
    unsigned short* Qs_b = Ws_b + 3 * (size_t)NW;
    unsigned short* Rs_b = Qs_b + 3 * (size_t)NQ;

    const int prep_grid = (NW + NQ + NR + G4 + 255) / 256;
    prep8<<<prep_grid, 256, 0, stream>>>(Wih_f, Whh_f, bih_f, bhh_f, Q_f, R_f,
                                         Ws_f, Qs_f, Rs_f, bP_f);
    prep8<<<prep_grid, 256, 0, stream>>>(Wih_b, Whh_b, bih_b, bhh_b, Q_b, R_b,
                                         Ws_b, Qs_b, Rs_b, bP_b);
    lstm13<<<64, 512, 0, stream>>>(words, embd, Qs_f, Rs_f, Ws_f, bP_f,
                                   Qs_b, Rs_b, Ws_b, bP_b, hf, hb);
    logits_kernel<<<128, 256, 0, stream>>>(hf, hb, Wt, bt, out);
}

// Round 18
// 3993.835 us; speedup vs baseline: 2.7271x; 2.7271x over previous
//
#include <hip/hip_runtime.h>
#include <math.h>

// Problem dims
#define TT 128
#define BB 512
#define EE 100
#define HH 256
#define G4 1024       // 4*H
#define NTAG 20
#define KP 368        // padded K (356 -> 368, zeros in PW)
#define PWPSZ (KP * G4)       // 376832
#define QPSZ  25600           // 64 kq * 400
#define RPSZ  28672           // 28 kq * 1024 (kq 25..27 zero-padded)

__device__ __forceinline__ float sigm(float x) { return 1.0f / (1.0f + expf(-x)); }

// ---------------------------------------------------------------------------
// prep6 (one direction): PWp[k][n] packed weights k<100 = Wih^T, 100..355 =
// Whh^T, 356..367 = 0. QP[kq][e][kk] = Q[kq*4+kk][e] (k-quad packed).
// RP[kq][j][kk] = R[kq*4+kk][j], zero for k >= 100. bP[n] = bih[n]+bhh[n].
// ---------------------------------------------------------------------------
__global__ void prep6(const float* __restrict__ Wih, const float* __restrict__ Whh,
                      const float* __restrict__ bih, const float* __restrict__ bhh,
                      const float* __restrict__ Q, const float* __restrict__ R,
                      float* __restrict__ PWp, float* __restrict__ QP,
                      float* __restrict__ RP, float* __restrict__ bP)
{
    int idx = blockIdx.x * blockDim.x + threadIdx.x;
    if (idx < PWPSZ) {
        int k = idx >> 10, n = idx & 1023;
        PWp[idx] = (k < EE) ? Wih[n * EE + k]
                 : (k < EE + HH) ? Whh[n * HH + (k - EE)] : 0.f;
    } else if (idx < PWPSZ + QPSZ) {
        int i = idx - PWPSZ;
        int kq = i / 400, rem = i - kq * 400;
        int e = rem >> 2, kk = rem & 3;
        QP[i] = Q[(kq * 4 + kk) * EE + e];
    } else if (idx < PWPSZ + QPSZ + RPSZ) {
        int i = idx - (PWPSZ + QPSZ);
        int kq = i >> 10, rem = i & 1023;
        int j = rem >> 2, kk = rem & 3;
        int k = kq * 4 + kk;
        RP[i] = (k < EE) ? R[k * HH + j] : 0.f;
    } else if (idx < PWPSZ + QPSZ + RPSZ + G4) {
        int n = idx - (PWPSZ + QPSZ + RPSZ);
        bP[n] = bih[n] + bhh[n];
    }
}

// ---- software-pipeline slot macros -----------------------------------------
// Pasted digit-suffixed names are ALWAYS parenthesized before member access.
// P1: 1 row/thread, K=256 as 64 k-quads; quad-dot per chunk. depth 4, no clamp.
#define P1L(S, kq) { \
    q##S = *(const float4*)(QP + (kq) * 400 + e * 4); \
    h##S = *(const float4*)(sH + r1 * HH + (kq) * 4); }
#define P1F(S) { a0 += (h##S).x*(q##S).x + (h##S).y*(q##S).y + (h##S).z*(q##S).z + (h##S).w*(q##S).w; }

// P2: 2 rows/thread, K as 28 k-quads (25 real + 3 zero-weight). depth 4, no clamp.
#define P2L(S, kq) { \
    r##S = *(const float4*)(RP + (kq) * 1024 + j2 * 4); \
    X##S##0 = *(const float4*)(sA + r20 * KP + (kq) * 4); \
    X##S##1 = *(const float4*)(sA + r21 * KP + (kq) * 4); }
#define P2F(S) { \
    s0 += (X##S##0).x*(r##S).x + (X##S##0).y*(r##S).y + (X##S##0).z*(r##S).z + (X##S##0).w*(r##S).w; \
    s1 += (X##S##1).x*(r##S).x + (X##S##1).y*(r##S).y + (X##S##1).z*(r##S).z + (X##S##1).w*(r##S).w; }

// P3: 4 cols x 2 rows/thread, merged K=368 (4-k chunks); clamp at k=364. depth 4.
#define P3L(S, kk) { const int kc_ = ((kk) <= 364) ? (kk) : 364; \
    const float* wp_ = PW + (size_t)kc_ * G4 + n0; \
    W##S##0 = *(const float4*)(wp_);        W##S##1 = *(const float4*)(wp_ + G4); \
    W##S##2 = *(const float4*)(wp_ + 2*G4); W##S##3 = *(const float4*)(wp_ + 3*G4); \
    const float* xp_ = sA + rg3 * KP + kc_; \
    X##S##0 = *(const float4*)(xp_);        X##S##1 = *(const float4*)(xp_ + KP); }
#define P3F(S) { \
    a00 += (X##S##0).x*(W##S##0).x + (X##S##0).y*(W##S##1).x + (X##S##0).z*(W##S##2).x + (X##S##0).w*(W##S##3).x; \
    a01 += (X##S##0).x*(W##S##0).y + (X##S##0).y*(W##S##1).y + (X##S##0).z*(W##S##2).y + (X##S##0).w*(W##S##3).y; \
    a02 += (X##S##0).x*(W##S##0).z + (X##S##0).y*(W##S##1).z + (X##S##0).z*(W##S##2).z + (X##S##0).w*(W##S##3).z; \
    a03 += (X##S##0).x*(W##S##0).w + (X##S##0).y*(W##S##1).w + (X##S##0).z*(W##S##2).w + (X##S##0).w*(W##S##3).w; \
    a10 += (X##S##1).x*(W##S##0).x + (X##S##1).y*(W##S##1).x + (X##S##1).z*(W##S##2).x + (X##S##1).w*(W##S##3).x; \
    a11 += (X##S##1).x*(W##S##0).y + (X##S##1).y*(W##S##1).y + (X##S##1).z*(W##S##2).y + (X##S##1).w*(W##S##3).y; \
    a12 += (X##S##1).x*(W##S##0).z + (X##S##1).y*(W##S##1).z + (X##S##1).z*(W##S##2).z + (X##S##1).w*(W##S##3).z; \
    a13 += (X##S##1).x*(W##S##0).w + (X##S##1).y*(W##S##1).w + (X##S##1).z*(W##S##2).w + (X##S##1).w*(W##S##3).w; }

// ---------------------------------------------------------------------------
// Main recurrence. 256 fully-independent blocks (128 chunks x 2 dirs), 512
// threads, 4 batch rows, all 1024 gate cols. LDS-pipe-lean layout:
// (C,R)=(4,2) in phase 3 (1 broadcast b128 per 16 FMA), k-quad-packed Q/R
// (1 coalesced b128 per chunk in p1/p2).
// ---------------------------------------------------------------------------
__global__ __launch_bounds__(512, 1) void lstm6(
    const int* __restrict__ words, const float* __restrict__ embed,
    const float* __restrict__ QPf, const float* __restrict__ RPf,
    const float* __restrict__ PWf, const float* __restrict__ bPf,
    const float* __restrict__ QPb, const float* __restrict__ RPb,
    const float* __restrict__ PWb, const float* __restrict__ bPb,
    float* hfbuf, float* hbbuf)
{
    const int bid = blockIdx.x;
    const int dir = bid & 1;
    const int cb  = bid >> 1;         // 0..127
    const int b0  = cb * 4;
    const int tid = threadIdx.x;

    const float* QP = dir ? QPb : QPf;
    const float* RP = dir ? RPb : RPf;
    const float* PW = dir ? PWb : PWf;
    const float* bP = dir ? bPb : bPf;
    float* hout = dir ? hbbuf : hfbuf;

    __shared__ alignas(16) float sA[4 * KP];     // [xm(100)|hm(256)|pad12] per row
    __shared__ alignas(16) float sH[4 * HH];     // h_prev rows
    __shared__ alignas(16) float sG[4 * G4];     // gate pre-activations (16 KB)
    __shared__ int sWords[4 * TT];               // word ids, preloaded

    // phase-1 ids: 1 row x 1 e-col
    const int e  = tid & 127;
    const int r1 = tid >> 7;                     // 0..3
    // phase-2 ids: 2 rows x 1 j-col
    const int j2  = tid & 255;
    const int r20 = (tid >> 8) * 2, r21 = r20 + 1;
    // phase-3 ids: 2 rows x 4 cols
    const int n0  = (tid & 255) * 4;
    const int rg3 = (tid >> 8) * 2;
    // phase-4 ids: 2 rows x 1 col; cell state in registers
    const int j4  = tid & 255;
    const int r4a = (tid >> 8) * 2, r4b = r4a + 1;
    float c0 = 0.f, c1 = 0.f;

    const float4 bv = *(const float4*)(bP + n0);   // hoisted bias

    // preload word ids; zero the 12-float K-pad of each sA row (read by P3
    // against zero weights -- must not contain NaN bit patterns)
    sWords[tid & 511] = words[(b0 + (tid >> 7)) * TT + (tid & 127)];
    if (tid < 48) {
        const int r = tid / 12, p = tid - r * 12;
        sA[r * KP + 356 + p] = 0.f;
    }
    __syncthreads();

    for (int s = 0; s < TT; ++s) {
        const int t = dir ? (TT - 1 - s) : s;

        // ---- phase 1: xm[r][e] = 2*sig(h_prev[r] . Q[:,e]) * x_t[r][e] ----
        if (e < EE) {
            const int w = sWords[r1 * TT + t];
            const float x = __builtin_nontemporal_load(&embed[(size_t)w * EE + e]);
            if (s == 0) {                 // h=0 -> 2*sig(0)=1 -> xm=x
                sA[r1 * KP + e] = x;
            } else {
                float a0 = 0.f;
                float4 qA, qB, qC, qD, hA, hB, hC, hD;
                P1L(A,0); P1L(B,1); P1L(C,2); P1L(D,3);
                for (int kb = 0; kb <= 56; kb += 4) {
                    P1F(A); P1L(A, kb+4); P1F(B); P1L(B, kb+5);
                    P1F(C); P1L(C, kb+6); P1F(D); P1L(D, kb+7);
                }
                P1F(A); P1F(B); P1F(C); P1F(D);   // kq = 60..63
                sA[r1 * KP + e] = 2.f * sigm(a0) * x;
            }
        }
        __syncthreads();

        // ---- phase 2: hm[r][j] = 2*sig(xm[r] . R[:,j]) * h_prev[r][j] ----
        // 28 k-quads: 25 real (k=0..99) + 3 zero-weight (X reads hit
        // initialized hm region; products are 0).
        if (s == 0) {
            sA[r20 * KP + EE + j2] = 0.f;
            sA[r21 * KP + EE + j2] = 0.f;
        } else {
            float s0 = 0.f, s1 = 0.f;
            float4 rA, rB, rC, rD;
            float4 XA0, XA1, XB0, XB1, XC0, XC1, XD0, XD1;
            P2L(A,0); P2L(B,1); P2L(C,2); P2L(D,3);
            for (int kb = 0; kb <= 20; kb += 4) {     // kb = 0,4,8,12,16,20
                P2F(A); P2L(A, kb+4); P2F(B); P2L(B, kb+5);
                P2F(C); P2L(C, kb+6); P2F(D); P2L(D, kb+7);
            }
            P2F(A); P2F(B); P2F(C); P2F(D);           // kq = 24,25,26,27
            sA[r20 * KP + EE + j2] = 2.f * sigm(s0) * sH[r20 * HH + j2];
            sA[r21 * KP + EE + j2] = 2.f * sigm(s1) * sH[r21 * HH + j2];
        }
        __syncthreads();

        // ---- phase 3: G = [xm|hm] @ PW + bias  (4 cols x 2 rows / thread) --
        {
            float a00=bv.x,a01=bv.y,a02=bv.z,a03=bv.w;
            float a10=bv.x,a11=bv.y,a12=bv.z,a13=bv.w;
            float4 WA0,WA1,WA2,WA3,XA0,XA1, WB0,WB1,WB2,WB3,XB0,XB1;
            float4 WC0,WC1,WC2,WC3,XC0,XC1, WD0,WD1,WD2,WD3,XD0,XD1;
            P3L(A,0); P3L(B,4); P3L(C,8); P3L(D,12);
            for (int kb = 0; kb <= 344; kb += 16) {
                P3F(A); P3L(A, kb+16); P3F(B); P3L(B, kb+20);
                P3F(C); P3L(C, kb+24); P3F(D); P3L(D, kb+28);
            }
            P3F(A); P3F(B);                       // k = 360, 364 (C,D dups)
            *(float4*)(sG + (rg3 + 0) * G4 + n0) = make_float4(a00,a01,a02,a03);
            *(float4*)(sG + (rg3 + 1) * G4 + n0) = make_float4(a10,a11,a12,a13);
        }
        __syncthreads();

        // ---- phase 4: cell update; h -> sH (LDS) + nt-store to hout[t] ----
        {
            const float gi0 = sG[r4a*G4 + j4],       gi1 = sG[r4b*G4 + j4];
            const float gf0 = sG[r4a*G4 + 256 + j4], gf1 = sG[r4b*G4 + 256 + j4];
            const float gg0 = sG[r4a*G4 + 512 + j4], gg1 = sG[r4b*G4 + 512 + j4];
            const float go0 = sG[r4a*G4 + 768 + j4], go1 = sG[r4b*G4 + 768 + j4];
            c0 = sigm(gf0) * c0 + sigm(gi0) * tanhf(gg0);
            c1 = sigm(gf1) * c1 + sigm(gi1) * tanhf(gg1);
            const float h0 = sigm(go0) * tanhf(c0);
            const float h1 = sigm(go1) * tanhf(c1);
            sH[r4a * HH + j4] = h0;
            sH[r4b * HH + j4] = h1;
            __builtin_nontemporal_store(h0, &hout[((size_t)t * BB + b0 + r4a) * HH + j4]);
            __builtin_nontemporal_store(h1, &hout[((size_t)t * BB + b0 + r4b) * HH + j4]);
        }
        __syncthreads();
    }
}

// ---------------------------------------------------------------------------
// logits = [hf|hb] @ Wt^T + bt ; argmax (first index on ties) -> out[b][t]
// ---------------------------------------------------------------------------
__global__ __launch_bounds__(256) void logits_kernel(
    const float* __restrict__ hf, const float* __restrict__ hb,
    const float* __restrict__ Wt, const float* __restrict__ bt,
    int* __restrict__ out)
{
    __shared__ float sW[NTAG][2 * HH];
    __shared__ float sb[NTAG];
    const int tid = threadIdx.x;
    for (int i = tid; i < NTAG * 2 * HH; i += 256) (&sW[0][0])[i] = Wt[i];
    if (tid < NTAG) sb[tid] = bt[tid];
    __syncthreads();

    const int pos = blockIdx.x * 256 + tid;
    const int b  = pos & 511;
    const int t0 = pos >> 9;
    const int t1 = t0 + 64;

    float acc0[NTAG], acc1[NTAG];
    #pragma unroll
    for (int n = 0; n < NTAG; ++n) { acc0[n] = sb[n]; acc1[n] = sb[n]; }

    const float* f0 = hf + ((size_t)t0 * BB + b) * HH;
    const float* f1 = hf + ((size_t)t1 * BB + b) * HH;
    for (int k = 0; k < HH; k += 4) {
        const float4 a0 = *(const float4*)(f0 + k);
        const float4 a1 = *(const float4*)(f1 + k);
        #pragma unroll
        for (int n = 0; n < NTAG; ++n) {
            const float4 w = *(const float4*)&sW[n][k];
            acc0[n] += a0.x * w.x + a0.y * w.y + a0.z * w.z + a0.w * w.w;
            acc1[n] += a1.x * w.x + a1.y * w.y + a1.z * w.z + a1.w * w.w;
        }
    }
    const float* g0 = hb + ((size_t)t0 * BB + b) * HH;
    const float* g1 = hb + ((size_t)t1 * BB + b) * HH;
    for (int k = 0; k < HH; k += 4) {
        const float4 a0 = *(const float4*)(g0 + k);
        const float4 a1 = *(const float4*)(g1 + k);
        #pragma unroll
        for (int n = 0; n < NTAG; ++n) {
            const float4 w = *(const float4*)&sW[n][HH + k];
            acc0[n] += a0.x * w.x + a0.y * w.y + a0.z * w.z + a0.w * w.w;
            acc1[n] += a1.x * w.x + a1.y * w.y + a1.z * w.z + a1.w * w.w;
        }
    }

    float b0v = acc0[0]; int i0 = 0;
    float b1v = acc1[0]; int i1 = 0;
    #pragma unroll
    for (int n = 1; n < NTAG; ++n) {
        if (acc0[n] > b0v) { b0v = acc0[n]; i0 = n; }
        if (acc1[n] > b1v) { b1v = acc1[n]; i1 = n; }
    }
    out[b * TT + t0] = i0;
    out[b * TT + t1] = i1;
}

// ---------------------------------------------------------------------------
extern "C" void kernel_launch(void* const* d_in, const int* in_sizes, int n_in,
                              void* d_out, int out_size, void* d_ws, size_t ws_size,
                              hipStream_t stream)
{
    (void)in_sizes; (void)n_in; (void)out_size; (void)ws_size;

    const int*   words = (const int*)  d_in[0];
    const float* embd  = (const float*)d_in[5];
    const float* Wih_f = (const float*)d_in[6];
    const float* Whh_f = (const float*)d_in[7];
    const float* bih_f = (const float*)d_in[8];
    const float* bhh_f = (const float*)d_in[9];
    const float* Q_f   = (const float*)d_in[10];
    const float* R_f   = (const float*)d_in[11];
    const float* Wih_b = (const float*)d_in[12];
    const float* Whh_b = (const float*)d_in[13];
    const float* bih_b = (const float*)d_in[14];
    const float* bhh_b = (const float*)d_in[15];
    const float* Q_b   = (const float*)d_in[16];
    const float* R_b   = (const float*)d_in[17];
    const float* Wt    = (const float*)d_in[18];
    const float* bt    = (const float*)d_in[19];
    int* out = (int*)d_out;

    // workspace layout (floats), total ~138 MB
    float* ws   = (float*)d_ws;
    float* PW_f = ws;                         // 376832
    float* QP_f = PW_f + PWPSZ;               // 25600
    float* RP_f = QP_f + QPSZ;                // 28672
    float* bP_f = RP_f + RPSZ;                // 1024
    float* PW_b = bP_f + G4;
    float* QP_b = PW_b + PWPSZ;
    float* RP_b = QP_b + QPSZ;
    float* bP_b = RP_b + RPSZ;
    float* hf   = bP_b + G4;                  // 16777216
    float* hb   = hf + (size_t)TT * BB * HH;  // 16777216

    const int prep_grid = (PWPSZ + QPSZ + RPSZ + G4 + 255) / 256;
    prep6<<<prep_grid, 256, 0, stream>>>(Wih_f, Whh_f, bih_f, bhh_f, Q_f, R_f,
                                         PW_f, QP_f, RP_f, bP_f);
    prep6<<<prep_grid, 256, 0, stream>>>(Wih_b, Whh_b, bih_b, bhh_b, Q_b, R_b,
                                         PW_b, QP_b, RP_b, bP_b);
    lstm6<<<256, 512, 0, stream>>>(words, embd, QP_f, RP_f, PW_f, bP_f,
                                   QP_b, RP_b, PW_b, bP_b, hf, hb);
    logits_kernel<<<128, 256, 0, stream>>>(hf, hb, Wt, bt, out);
}

// Round 19
// 3953.121 us; speedup vs baseline: 2.7552x; 1.0103x over previous
//
#include <hip/hip_runtime.h>
#include <math.h>

// Problem dims
#define TT 128
#define BB 512
#define EE 100
#define HH 256
#define G4 1024       // 4*H
#define NTAG 20
#define KP 368        // padded K (356 -> 368, zeros in PW)
#define PWPSZ (KP * G4)       // 376832
#define QPSZ  25600           // 64 kq * 400
#define RPSZ  28672           // 28 kq * 1024 (kq 25..27 zero-padded)

__device__ __forceinline__ float sigm(float x) { return 1.0f / (1.0f + expf(-x)); }

// ---------------------------------------------------------------------------
// prep9 (one direction): PW GATE-INTERLEAVED packing: PWp[k][4j+g] =
// W[k][n=g*256+j] (k<100: Wih^T, 100..355: Whh^T, else 0) -> a thread's 4
// contiguous cols are the (i,f,g,o) gates of ONE column j => phase 4 is
// register-local. bP[4j+g] = bih[n]+bhh[n] likewise.
// QP[kq][e][kk] = Q[kq*4+kk][e]; RP[kq][j][kk] = R[kq*4+kk][j] (0 for k>=100).
// ---------------------------------------------------------------------------
__global__ void prep9(const float* __restrict__ Wih, const float* __restrict__ Whh,
                      const float* __restrict__ bih, const float* __restrict__ bhh,
                      const float* __restrict__ Q, const float* __restrict__ R,
                      float* __restrict__ PWp, float* __restrict__ QP,
                      float* __restrict__ RP, float* __restrict__ bP)
{
    int idx = blockIdx.x * blockDim.x + threadIdx.x;
    if (idx < PWPSZ) {
        int k = idx >> 10, p = idx & 1023;
        int n = (p & 3) * 256 + (p >> 2);          // gate-interleaved
        PWp[idx] = (k < EE) ? Wih[n * EE + k]
                 : (k < EE + HH) ? Whh[n * HH + (k - EE)] : 0.f;
    } else if (idx < PWPSZ + QPSZ) {
        int i = idx - PWPSZ;
        int kq = i / 400, rem = i - kq * 400;
        int e = rem >> 2, kk = rem & 3;
        QP[i] = Q[(kq * 4 + kk) * EE + e];
    } else if (idx < PWPSZ + QPSZ + RPSZ) {
        int i = idx - (PWPSZ + QPSZ);
        int kq = i >> 10, rem = i & 1023;
        int j = rem >> 2, kk = rem & 3;
        int k = kq * 4 + kk;
        RP[i] = (k < EE) ? R[k * HH + j] : 0.f;
    } else if (idx < PWPSZ + QPSZ + RPSZ + G4) {
        int p = idx - (PWPSZ + QPSZ + RPSZ);
        int n = (p & 3) * 256 + (p >> 2);
        bP[p] = bih[n] + bhh[n];
    }
}

// ---- software-pipeline slot macros (identical structure to R10/R18) --------
// P1: 1 row/thread, K=256 as 64 k-quads. depth 4, no clamp.
#define P1L(S, kq) { \
    q##S = *(const float4*)(QP + (kq) * 400 + e * 4); \
    h##S = *(const float4*)(sH + r1 * HH + (kq) * 4); }
#define P1F(S) { a0 += (h##S).x*(q##S).x + (h##S).y*(q##S).y + (h##S).z*(q##S).z + (h##S).w*(q##S).w; }

// P2: 2 rows/thread, K as 28 k-quads (25 real + 3 zero-weight). depth 4.
#define P2L(S, kq) { \
    r##S = *(const float4*)(RP + (kq) * 1024 + j2 * 4); \
    X##S##0 = *(const float4*)(sA + r20 * KP + (kq) * 4); \
    X##S##1 = *(const float4*)(sA + r21 * KP + (kq) * 4); }
#define P2F(S) { \
    s0 += (X##S##0).x*(r##S).x + (X##S##0).y*(r##S).y + (X##S##0).z*(r##S).z + (X##S##0).w*(r##S).w; \
    s1 += (X##S##1).x*(r##S).x + (X##S##1).y*(r##S).y + (X##S##1).z*(r##S).z + (X##S##1).w*(r##S).w; }

// P3: 4 cols x 2 rows/thread, merged K=368 (4-k chunks); clamp at 364. depth 4.
#define P3L(S, kk) { const int kc_ = ((kk) <= 364) ? (kk) : 364; \
    const float* wp_ = PW + (size_t)kc_ * G4 + n0; \
    W##S##0 = *(const float4*)(wp_);        W##S##1 = *(const float4*)(wp_ + G4); \
    W##S##2 = *(const float4*)(wp_ + 2*G4); W##S##3 = *(const float4*)(wp_ + 3*G4); \
    const float* xp_ = sA + rg3 * KP + kc_; \
    X##S##0 = *(const float4*)(xp_);        X##S##1 = *(const float4*)(xp_ + KP); }
#define P3F(S) { \
    a00 += (X##S##0).x*(W##S##0).x + (X##S##0).y*(W##S##1).x + (X##S##0).z*(W##S##2).x + (X##S##0).w*(W##S##3).x; \
    a01 += (X##S##0).x*(W##S##0).y + (X##S##0).y*(W##S##1).y + (X##S##0).z*(W##S##2).y + (X##S##0).w*(W##S##3).y; \
    a02 += (X##S##0).x*(W##S##0).z + (X##S##0).y*(W##S##1).z + (X##S##0).z*(W##S##2).z + (X##S##0).w*(W##S##3).z; \
    a03 += (X##S##0).x*(W##S##0).w + (X##S##0).y*(W##S##1).w + (X##S##0).z*(W##S##2).w + (X##S##0).w*(W##S##3).w; \
    a10 += (X##S##1).x*(W##S##0).x + (X##S##1).y*(W##S##1).x + (X##S##1).z*(W##S##2).x + (X##S##1).w*(W##S##3).x; \
    a11 += (X##S##1).x*(W##S##0).y + (X##S##1).y*(W##S##1).y + (X##S##1).z*(W##S##2).y + (X##S##1).w*(W##S##3).y; \
    a12 += (X##S##1).x*(W##S##0).z + (X##S##1).y*(W##S##1).z + (X##S##1).z*(W##S##2).z + (X##S##1).w*(W##S##3).z; \
    a13 += (X##S##1).x*(W##S##0).w + (X##S##1).y*(W##S##1).w + (X##S##1).z*(W##S##2).w + (X##S##1).w*(W##S##3).w; }

// ---------------------------------------------------------------------------
// Main recurrence. 256 independent blocks (128 chunks x 2 dirs), 512 thr,
// 4 batch rows, 1024 gate cols. R10 structure with gate-interleaved W:
// a thread's acc quad = (i,f,g,o) of ONE column j -> phase 4 fused into
// phase 3 (register-local), sG deleted, 3 barriers/step instead of 4.
// ---------------------------------------------------------------------------
__global__ __launch_bounds__(512, 1) void lstm14(
    const int* __restrict__ words, const float* __restrict__ embed,
    const float* __restrict__ QPf, const float* __restrict__ RPf,
    const float* __restrict__ PWf, const float* __restrict__ bPf,
    const float* __restrict__ QPb, const float* __restrict__ RPb,
    const float* __restrict__ PWb, const float* __restrict__ bPb,
    float* hfbuf, float* hbbuf)
{
    const int bid = blockIdx.x;
    const int dir = bid & 1;
    const int cb  = bid >> 1;         // 0..127
    const int b0  = cb * 4;
    const int tid = threadIdx.x;

    const float* QP = dir ? QPb : QPf;
    const float* RP = dir ? RPb : RPf;
    const float* PW = dir ? PWb : PWf;
    const float* bP = dir ? bPb : bPf;
    float* hout = dir ? hbbuf : hfbuf;

    __shared__ alignas(16) float sA[4 * KP];     // [xm(100)|hm(256)|pad12] per row
    __shared__ alignas(16) float sH[4 * HH];     // h_prev rows
    __shared__ int sWords[4 * TT];               // word ids, preloaded

    // phase-1 ids: 1 row x 1 e-col
    const int e  = tid & 127;
    const int r1 = tid >> 7;                     // 0..3
    // phase-2 ids: 2 rows x 1 j-col
    const int j2  = tid & 255;
    const int r20 = (tid >> 8) * 2, r21 = r20 + 1;
    // phase-3/4 ids: 1 col j (4 gates) x 2 rows; cell state in registers
    const int jj  = tid & 255;                   // column j
    const int n0  = jj * 4;                      // packed col base (i,f,g,o)
    const int rg3 = (tid >> 8) * 2;              // rows rg3, rg3+1
    float c0 = 0.f, c1 = 0.f;

    const float4 bv = *(const float4*)(bP + n0);   // (bi, bf, bg, bo) of col j

    // preload word ids; zero the 12-float K-pad of each sA row
    sWords[tid & 511] = words[(b0 + (tid >> 7)) * TT + (tid & 127)];
    if (tid < 48) {
        const int r = tid / 12, p = tid - r * 12;
        sA[r * KP + 356 + p] = 0.f;
    }
    __syncthreads();

    for (int s = 0; s < TT; ++s) {
        const int t = dir ? (TT - 1 - s) : s;

        // ---- phase 1: xm[r][e] = 2*sig(h_prev[r] . Q[:,e]) * x_t[r][e] ----
        if (e < EE) {
            const int w = sWords[r1 * TT + t];
            const float x = __builtin_nontemporal_load(&embed[(size_t)w * EE + e]);
            if (s == 0) {                 // h=0 -> 2*sig(0)=1 -> xm=x
                sA[r1 * KP + e] = x;
            } else {
                float a0 = 0.f;
                float4 qA, qB, qC, qD, hA, hB, hC, hD;
                P1L(A,0); P1L(B,1); P1L(C,2); P1L(D,3);
                for (int kb = 0; kb <= 56; kb += 4) {
                    P1F(A); P1L(A, kb+4); P1F(B); P1L(B, kb+5);
                    P1F(C); P1L(C, kb+6); P1F(D); P1L(D, kb+7);
                }
                P1F(A); P1F(B); P1F(C); P1F(D);   // kq = 60..63
                sA[r1 * KP + e] = 2.f * sigm(a0) * x;
            }
        }
        __syncthreads();

        // ---- phase 2: hm[r][j] = 2*sig(xm[r] . R[:,j]) * h_prev[r][j] ----
        if (s == 0) {
            sA[r20 * KP + EE + j2] = 0.f;
            sA[r21 * KP + EE + j2] = 0.f;
        } else {
            float s0 = 0.f, s1 = 0.f;
            float4 rA, rB, rC, rD;
            float4 XA0, XA1, XB0, XB1, XC0, XC1, XD0, XD1;
            P2L(A,0); P2L(B,1); P2L(C,2); P2L(D,3);
            for (int kb = 0; kb <= 20; kb += 4) {     // kb = 0,4,8,12,16,20
                P2F(A); P2L(A, kb+4); P2F(B); P2L(B, kb+5);
                P2F(C); P2L(C, kb+6); P2F(D); P2L(D, kb+7);
            }
            P2F(A); P2F(B); P2F(C); P2F(D);           // kq = 24,25,26,27
            sA[r20 * KP + EE + j2] = 2.f * sigm(s0) * sH[r20 * HH + j2];
            sA[r21 * KP + EE + j2] = 2.f * sigm(s1) * sH[r21 * HH + j2];
        }
        __syncthreads();

        // ---- phase 3+4 fused: G quad = (i,f,g,o) of col j; cell update ----
        {
            float a00=bv.x,a01=bv.y,a02=bv.z,a03=bv.w;
            float a10=bv.x,a11=bv.y,a12=bv.z,a13=bv.w;
            float4 WA0,WA1,WA2,WA3,XA0,XA1, WB0,WB1,WB2,WB3,XB0,XB1;
            float4 WC0,WC1,WC2,WC3,XC0,XC1, WD0,WD1,WD2,WD3,XD0,XD1;
            P3L(A,0); P3L(B,4); P3L(C,8); P3L(D,12);
            for (int kb = 0; kb <= 344; kb += 16) {
                P3F(A); P3L(A, kb+16); P3F(B); P3L(B, kb+20);
                P3F(C); P3L(C, kb+24); P3F(D); P3L(D, kb+28);
            }
            P3F(A); P3F(B);                       // k = 360, 364 (C,D dups)
            // register-local cell update (a00..a03 = gi,gf,gg,go of row rg3)
            c0 = sigm(a01) * c0 + sigm(a00) * tanhf(a02);
            c1 = sigm(a11) * c1 + sigm(a10) * tanhf(a12);
            const float h0 = sigm(a03) * tanhf(c0);
            const float h1 = sigm(a13) * tanhf(c1);
            sH[rg3 * HH + jj]       = h0;
            sH[(rg3 + 1) * HH + jj] = h1;
            __builtin_nontemporal_store(h0, &hout[((size_t)t * BB + b0 + rg3)     * HH + jj]);
            __builtin_nontemporal_store(h1, &hout[((size_t)t * BB + b0 + rg3 + 1) * HH + jj]);
        }
        __syncthreads();
    }
}

// ---------------------------------------------------------------------------
// logits = [hf|hb] @ Wt^T + bt ; argmax (first index on ties) -> out[b][t]
// 256 blocks x 256 threads, 1 position/thread (2x parallelism vs R10).
// ---------------------------------------------------------------------------
__global__ __launch_bounds__(256) void logits_kernel(
    const float* __restrict__ hf, const float* __restrict__ hb,
    const float* __restrict__ Wt, const float* __restrict__ bt,
    int* __restrict__ out)
{
    __shared__ float sW[NTAG][2 * HH];
    __shared__ float sb[NTAG];
    const int tid = threadIdx.x;
    for (int i = tid; i < NTAG * 2 * HH; i += 256) (&sW[0][0])[i] = Wt[i];
    if (tid < NTAG) sb[tid] = bt[tid];
    __syncthreads();

    const int pos = blockIdx.x * 256 + tid;   // 0..65535
    const int b = pos & 511;
    const int t = pos >> 9;                   // 0..127

    float acc0[NTAG];
    #pragma unroll
    for (int n = 0; n < NTAG; ++n) acc0[n] = sb[n];

    const float* f0 = hf + ((size_t)t * BB + b) * HH;
    for (int k = 0; k < HH; k += 4) {
        const float4 a0 = *(const float4*)(f0 + k);
        #pragma unroll
        for (int n = 0; n < NTAG; ++n) {
            const float4 w = *(const float4*)&sW[n][k];
            acc0[n] += a0.x * w.x + a0.y * w.y + a0.z * w.z + a0.w * w.w;
        }
    }
    const float* g0 = hb + ((size_t)t * BB + b) * HH;
    for (int k = 0; k < HH; k += 4) {
        const float4 a0 = *(const float4*)(g0 + k);
        #pragma unroll
        for (int n = 0; n < NTAG; ++n) {
            const float4 w = *(const float4*)&sW[n][HH + k];
            acc0[n] += a0.x * w.x + a0.y * w.y + a0.z * w.z + a0.w * w.w;
        }
    }

    float b0v = acc0[0]; int i0 = 0;
    #pragma unroll
    for (int n = 1; n < NTAG; ++n) {
        if (acc0[n] > b0v) { b0v = acc0[n]; i0 = n; }
    }
    out[b * TT + t] = i0;
}

// ---------------------------------------------------------------------------
extern "C" void kernel_launch(void* const* d_in, const int* in_sizes, int n_in,
                              void* d_out, int out_size, void* d_ws, size_t ws_size,
                              hipStream_t stream)
{
    (void)in_sizes; (void)n_in; (void)out_size; (void)ws_size;

    const int*   words = (const int*)  d_in[0];
    const float* embd  = (const float*)d_in[5];
    const float* Wih_f = (const float*)d_in[6];
    const float* Whh_f = (const float*)d_in[7];
    const float* bih_f = (const float*)d_in[8];
    const float* bhh_f = (const float*)d_in[9];
    const float* Q_f   = (const float*)d_in[10];
    const float* R_f   = (const float*)d_in[11];
    const float* Wih_b = (const float*)d_in[12];
    const float* Whh_b = (const float*)d_in[13];
    const float* bih_b = (const float*)d_in[14];
    const float* bhh_b = (const float*)d_in[15];
    const float* Q_b   = (const float*)d_in[16];
    const float* R_b   = (const float*)d_in[17];
    const float* Wt    = (const float*)d_in[18];
    const float* bt    = (const float*)d_in[19];
    int* out = (int*)d_out;

    // workspace layout (floats), total ~138 MB
    float* ws   = (float*)d_ws;
    float* PW_f = ws;                         // 376832
    float* QP_f = PW_f + PWPSZ;               // 25600
    float* RP_f = QP_f + QPSZ;                // 28672
    float* bP_f = RP_f + RPSZ;                // 1024
    float* PW_b = bP_f + G4;
    float* QP_b = PW_b + PWPSZ;
    float* RP_b = QP_b + QPSZ;
    float* bP_b = RP_b + RPSZ;
    float* hf   = bP_b + G4;                  // 16777216
    float* hb   = hf + (size_t)TT * BB * HH;  // 16777216

    const int prep_grid = (PWPSZ + QPSZ + RPSZ + G4 + 255) / 256;
    prep9<<<prep_grid, 256, 0, stream>>>(Wih_f, Whh_f, bih_f, bhh_f, Q_f, R_f,
                                         PW_f, QP_f, RP_f, bP_f);
    prep9<<<prep_grid, 256, 0, stream>>>(Wih_b, Whh_b, bih_b, bhh_b, Q_b, R_b,
                                         PW_b, QP_b, RP_b, bP_b);
    lstm14<<<256, 512, 0, stream>>>(words, embd, QP_f, RP_f, PW_f, bP_f,
                                    QP_b, RP_b, PW_b, bP_b, hf, hb);
    logits_kernel<<<256, 256, 0, stream>>>(hf, hb, Wt, bt, out);
}